// Round 1
// baseline (616.414 us; speedup 1.0000x reference)
//
#include <hip/hip_runtime.h>
#include <hip/hip_bf16.h>

#define NH 16
#define HDIM 64
#define NB 2
#define NSEQ 2048
#define DMODEL 1024
#define MROWS (NB * NSEQ)   // 4096

typedef __attribute__((ext_vector_type(8))) short bf16x8;
typedef __attribute__((ext_vector_type(4))) float f32x4;

static __device__ inline unsigned short f2bf(float f) {
    union { float f; unsigned u; } v;
    v.f = f;
    unsigned r = v.u + 0x7fffu + ((v.u >> 16) & 1u);   // RNE
    return (unsigned short)(r >> 16);
}

// ---------------------------------------------------------------------------
// Kernel 1: convert x -> bf16 (row-major), weights -> bf16 TRANSPOSED
// (Wt[c][k] = W[k][c]) so GEMM B-operand fragments are contiguous 16B loads.
// ---------------------------------------------------------------------------
__global__ __launch_bounds__(256) void convert_kernel(
    const float* __restrict__ x,
    const float* __restrict__ wq, const float* __restrict__ wk,
    const float* __restrict__ wv, const float* __restrict__ wo,
    unsigned short* __restrict__ xb,
    unsigned short* __restrict__ wqt, unsigned short* __restrict__ wkt,
    unsigned short* __restrict__ wvt, unsigned short* __restrict__ wot)
{
    int tid = blockIdx.x * blockDim.x + threadIdx.x;   // 0 .. 1048575
    int sel = blockIdx.y;
    if (sel == 0) {
        long total = (long)MROWS * DMODEL;             // 4194304
        long stride = (long)gridDim.x * blockDim.x;    // 1048576
        for (long i = tid; i < total; i += stride)
            xb[i] = f2bf(x[i]);
    } else {
        const float* w = (sel == 1) ? wq : (sel == 2) ? wk : (sel == 3) ? wv : wo;
        unsigned short* wt = (sel == 1) ? wqt : (sel == 2) ? wkt : (sel == 3) ? wvt : wot;
        int c = tid >> 10;
        int k = tid & 1023;
        wt[tid] = f2bf(w[k * DMODEL + c]);             // coalesced write, L2-served read
    }
}

// ---------------------------------------------------------------------------
// QKV GEMM: C = A[4096x1024] * Bt^T, Bt is [1024][1024] col-major weights.
// blockIdx.z selects {Q, K, V}. Q/K written [b,h,n,hd]; V written [b,h,hd,n].
// Block = 4 waves; block tile 64x64; each wave: 16 rows x 64 cols.
// ---------------------------------------------------------------------------
__global__ __launch_bounds__(256) void qkv_gemm_kernel(
    const unsigned short* __restrict__ A,
    const unsigned short* __restrict__ Wqt,
    const unsigned short* __restrict__ Wkt,
    const unsigned short* __restrict__ Wvt,
    unsigned short* __restrict__ Qo,
    unsigned short* __restrict__ Ko,
    unsigned short* __restrict__ Vto)
{
    int z = blockIdx.z;
    const unsigned short* Bt = (z == 0) ? Wqt : (z == 1) ? Wkt : Wvt;

    int wave = threadIdx.x >> 6;
    int lane = threadIdx.x & 63;
    int l16 = lane & 15, quad = lane >> 4;
    int n0 = blockIdx.x * 64;
    int m0 = blockIdx.y * 64 + wave * 16;

    const unsigned short* ap = A  + (long)(m0 + l16) * DMODEL + quad * 8;
    const unsigned short* bp = Bt + (long)(n0 + l16) * DMODEL + quad * 8;

    f32x4 acc[4] = {{0,0,0,0},{0,0,0,0},{0,0,0,0},{0,0,0,0}};
    for (int kk = 0; kk < DMODEL; kk += 32) {
        bf16x8 a = *(const bf16x8*)(ap + kk);
#pragma unroll
        for (int j = 0; j < 4; j++) {
            bf16x8 b = *(const bf16x8*)(bp + (long)j * 16 * DMODEL + kk);
            acc[j] = __builtin_amdgcn_mfma_f32_16x16x32_bf16(a, b, acc[j], 0, 0, 0);
        }
    }

#pragma unroll
    for (int j = 0; j < 4; j++) {
        int c = n0 + j * 16 + l16;
        int h = c >> 6, hd = c & 63;
#pragma unroll
        for (int r = 0; r < 4; r++) {
            int rr = m0 + quad * 4 + r;
            int b_ = rr >> 11, n_ = rr & (NSEQ - 1);
            unsigned short v = f2bf(acc[j][r]);
            if (z == 2)
                Vto[((long)(b_ * NH + h) * HDIM + hd) * NSEQ + n_] = v;
            else if (z == 0)
                Qo[((long)(b_ * NH + h) * NSEQ + n_) * HDIM + hd] = v;
            else
                Ko[((long)(b_ * NH + h) * NSEQ + n_) * HDIM + hd] = v;
        }
    }
}

// ---------------------------------------------------------------------------
// Flash attention with ALiBi + causal. 1 wave/block, 16 queries/wave,
// 32-key chunks. S = Q*K^T via 2 mfma pairs, online softmax, P routed
// through LDS (C-layout -> A-layout), PV via 4 mfma. ctx written bf16
// in [b, n, h, hd] so the output projection reads it as [4096][1024].
// ---------------------------------------------------------------------------
__global__ __launch_bounds__(64) void attn_kernel(
    const unsigned short* __restrict__ Q,
    const unsigned short* __restrict__ K,
    const unsigned short* __restrict__ Vt,
    unsigned short* __restrict__ ctx)
{
    __shared__ unsigned short Pl[16][32];

    int lane = threadIdx.x;
    int l16 = lane & 15, quad = lane >> 4;
    int bh = blockIdx.y;            // b*16 + h
    int qb = blockIdx.x * 16;
    int b_ = bh >> 4, h = bh & 15;
    float slope = exp2f(-0.5f * (float)(h + 1));
    const float scale = 0.125f;     // 1/sqrt(64)

    const unsigned short* qbase = Q + ((long)bh * NSEQ + qb + l16) * HDIM + quad * 8;
    bf16x8 aq0 = *(const bf16x8*)(qbase);
    bf16x8 aq1 = *(const bf16x8*)(qbase + 32);

    float m_r[4], l_r[4];
    f32x4 o[4] = {{0,0,0,0},{0,0,0,0},{0,0,0,0},{0,0,0,0}};
#pragma unroll
    for (int r = 0; r < 4; r++) { m_r[r] = -1e30f; l_r[r] = 0.0f; }

    int qEnd = qb + 15;
    for (int kb = 0; kb <= qEnd; kb += 32) {
        // ---- S = Q K^T for 16 queries x 32 keys (two 16-key tiles)
        const unsigned short* kbase = K + ((long)bh * NSEQ + kb + l16) * HDIM + quad * 8;
        bf16x8 k00 = *(const bf16x8*)(kbase);
        bf16x8 k01 = *(const bf16x8*)(kbase + 32);
        bf16x8 k10 = *(const bf16x8*)(kbase + 16 * HDIM);
        bf16x8 k11 = *(const bf16x8*)(kbase + 16 * HDIM + 32);
        f32x4 s0 = {0,0,0,0}, s1 = {0,0,0,0};
        s0 = __builtin_amdgcn_mfma_f32_16x16x32_bf16(aq0, k00, s0, 0, 0, 0);
        s0 = __builtin_amdgcn_mfma_f32_16x16x32_bf16(aq1, k01, s0, 0, 0, 0);
        s1 = __builtin_amdgcn_mfma_f32_16x16x32_bf16(aq0, k10, s1, 0, 0, 0);
        s1 = __builtin_amdgcn_mfma_f32_16x16x32_bf16(aq1, k11, s1, 0, 0, 0);

        // ---- alibi + causal mask + scale; row max (reduce across 16 lanes)
        float p0[4], p1[4], mx[4];
#pragma unroll
        for (int r = 0; r < 4; r++) {
            int i = qb + quad * 4 + r;
            int j0 = kb + l16, j1 = kb + 16 + l16;
            float v0 = (j0 <= i) ? (s0[r] - slope * (float)(i - j0)) * scale : -1e30f;
            float v1 = (j1 <= i) ? (s1[r] - slope * (float)(i - j1)) * scale : -1e30f;
            p0[r] = v0; p1[r] = v1;
            float mv = fmaxf(v0, v1);
            mv = fmaxf(mv, __shfl_xor(mv, 1));
            mv = fmaxf(mv, __shfl_xor(mv, 2));
            mv = fmaxf(mv, __shfl_xor(mv, 4));
            mv = fmaxf(mv, __shfl_xor(mv, 8));
            mx[r] = mv;
        }

        // ---- online softmax update
#pragma unroll
        for (int r = 0; r < 4; r++) {
            float mnew = fmaxf(m_r[r], mx[r]);
            float alpha = __expf(m_r[r] - mnew);
            m_r[r] = mnew;
            float e0 = __expf(p0[r] - mnew);
            float e1 = __expf(p1[r] - mnew);
            p0[r] = e0; p1[r] = e1;
            float sum = e0 + e1;
            sum += __shfl_xor(sum, 1);
            sum += __shfl_xor(sum, 2);
            sum += __shfl_xor(sum, 4);
            sum += __shfl_xor(sum, 8);
            l_r[r] = l_r[r] * alpha + sum;
#pragma unroll
            for (int cb = 0; cb < 4; cb++) o[cb][r] *= alpha;
        }

        // ---- P: C-layout -> LDS -> A-layout (bf16)
#pragma unroll
        for (int r = 0; r < 4; r++) {
            Pl[quad * 4 + r][l16]      = f2bf(p0[r]);
            Pl[quad * 4 + r][16 + l16] = f2bf(p1[r]);
        }
        __syncthreads();
        bf16x8 apf = *(const bf16x8*)&Pl[l16][quad * 8];

        // ---- O += P V  (V^T layout: [bh][hd][n], contiguous over keys)
        const unsigned short* vbase = Vt + ((long)bh * HDIM + l16) * NSEQ + kb + quad * 8;
#pragma unroll
        for (int cb = 0; cb < 4; cb++) {
            bf16x8 bv = *(const bf16x8*)(vbase + (long)cb * 16 * NSEQ);
            o[cb] = __builtin_amdgcn_mfma_f32_16x16x32_bf16(apf, bv, o[cb], 0, 0, 0);
        }
        __syncthreads();
    }

    // ---- normalize and store ctx [b, n, h, hd] as bf16
#pragma unroll
    for (int r = 0; r < 4; r++) {
        float inv = 1.0f / l_r[r];
        int n_ = qb + quad * 4 + r;
        long base = (((long)b_ * NSEQ + n_) * NH + h) * HDIM;
#pragma unroll
        for (int cb = 0; cb < 4; cb++)
            ctx[base + cb * 16 + l16] = f2bf(o[cb][r] * inv);
    }
}

// ---------------------------------------------------------------------------
// Output projection: out = ctx[4096x1024] @ Wo + bo, fp32 out.
// ---------------------------------------------------------------------------
__global__ __launch_bounds__(256) void out_gemm_kernel(
    const unsigned short* __restrict__ A,
    const unsigned short* __restrict__ Bt,
    float* __restrict__ out,
    const float* __restrict__ bias)
{
    int wave = threadIdx.x >> 6;
    int lane = threadIdx.x & 63;
    int l16 = lane & 15, quad = lane >> 4;
    int n0 = blockIdx.x * 64;
    int m0 = blockIdx.y * 64 + wave * 16;

    const unsigned short* ap = A  + (long)(m0 + l16) * DMODEL + quad * 8;
    const unsigned short* bp = Bt + (long)(n0 + l16) * DMODEL + quad * 8;

    f32x4 acc[4] = {{0,0,0,0},{0,0,0,0},{0,0,0,0},{0,0,0,0}};
    for (int kk = 0; kk < DMODEL; kk += 32) {
        bf16x8 a = *(const bf16x8*)(ap + kk);
#pragma unroll
        for (int j = 0; j < 4; j++) {
            bf16x8 b = *(const bf16x8*)(bp + (long)j * 16 * DMODEL + kk);
            acc[j] = __builtin_amdgcn_mfma_f32_16x16x32_bf16(a, b, acc[j], 0, 0, 0);
        }
    }

#pragma unroll
    for (int j = 0; j < 4; j++) {
        int c = n0 + j * 16 + l16;
        float bc = bias[c];
#pragma unroll
        for (int r = 0; r < 4; r++) {
            int rr = m0 + quad * 4 + r;
            out[(long)rr * DMODEL + c] = acc[j][r] + bc;
        }
    }
}

// ---------------------------------------------------------------------------
extern "C" void kernel_launch(void* const* d_in, const int* in_sizes, int n_in,
                              void* d_out, int out_size, void* d_ws, size_t ws_size,
                              hipStream_t stream)
{
    const float* x  = (const float*)d_in[0];
    const float* wq = (const float*)d_in[1];
    const float* wk = (const float*)d_in[2];
    const float* wv = (const float*)d_in[3];
    const float* wo = (const float*)d_in[4];
    const float* bo = (const float*)d_in[5];

    char* ws = (char*)d_ws;
    // workspace layout (48 MiB total)
    unsigned short* xb  = (unsigned short*)(ws);                        // 8 MiB
    unsigned short* wqt = (unsigned short*)(ws + (8L  << 20));          // 2 MiB
    unsigned short* wkt = (unsigned short*)(ws + (10L << 20));          // 2 MiB
    unsigned short* wvt = (unsigned short*)(ws + (12L << 20));          // 2 MiB
    unsigned short* wot = (unsigned short*)(ws + (14L << 20));          // 2 MiB
    unsigned short* Qb  = (unsigned short*)(ws + (16L << 20));          // 8 MiB
    unsigned short* Kb  = (unsigned short*)(ws + (24L << 20));          // 8 MiB
    unsigned short* Vt  = (unsigned short*)(ws + (32L << 20));          // 8 MiB
    unsigned short* ctx = (unsigned short*)(ws + (40L << 20));          // 8 MiB
    float* out = (float*)d_out;

    convert_kernel<<<dim3(4096, 5), 256, 0, stream>>>(
        x, wq, wk, wv, wo, xb, wqt, wkt, wvt, wot);

    qkv_gemm_kernel<<<dim3(DMODEL / 64, MROWS / 64, 3), 256, 0, stream>>>(
        xb, wqt, wkt, wvt, Qb, Kb, Vt);

    attn_kernel<<<dim3(NSEQ / 16, NB * NH), 64, 0, stream>>>(Qb, Kb, Vt, ctx);

    out_gemm_kernel<<<dim3(DMODEL / 64, MROWS / 64), 256, 0, stream>>>(
        ctx, wot, out, bo);
}

// Round 3
// 380.908 us; speedup vs baseline: 1.6183x; 1.6183x over previous
//
#include <hip/hip_runtime.h>
#include <hip/hip_bf16.h>
#include <stdint.h>

#define NH 16
#define HDIM 64
#define NB 2
#define NSEQ 2048
#define DM 1024
#define MROWS (NB * NSEQ)   // 4096

typedef __attribute__((ext_vector_type(8))) short bf16x8;
typedef __attribute__((ext_vector_type(4))) float f32x4;

static __device__ __forceinline__ unsigned short f2bf(float f) {
    union { float f; unsigned u; } v;
    v.f = f;
    unsigned r = v.u + 0x7fffu + ((v.u >> 16) & 1u);   // RNE
    return (unsigned short)(r >> 16);
}

typedef __attribute__((address_space(1))) void* gas_ptr;
typedef __attribute__((address_space(3))) void* las_ptr;

// async global->LDS, 16B per lane. LDS dest must be wave-uniform base + lane*16.
static __device__ __forceinline__ void load16_lds(const void* g, void* l) {
    __builtin_amdgcn_global_load_lds((gas_ptr)(uintptr_t)g, (las_ptr)(uintptr_t)l,
                                     16, 0, 0);
}

// ---------------------------------------------------------------------------
// Convert: x -> bf16 (blocks 0..1023, 1024 float4 each == exactly 4.19M floats),
// weights -> bf16 transposed via LDS tile transpose (blocks 1024..2047).
// Wq/Wk/Wv land in one fused [3072][1024] buffer; Wo in its own [1024][1024].
// ---------------------------------------------------------------------------
__global__ __launch_bounds__(256) void convert_kernel(
    const float* __restrict__ x,
    const float* __restrict__ wq, const float* __restrict__ wk,
    const float* __restrict__ wv, const float* __restrict__ wo,
    unsigned short* __restrict__ xb,
    unsigned short* __restrict__ wqkvt,
    unsigned short* __restrict__ wot)
{
    __shared__ unsigned short Ts[64][66];
    int t = threadIdx.x;
    int bx = blockIdx.x;
    if (bx < 1024) {
        // 1024 blocks * 4 iters * 256 threads * 1 float4 = 1,048,576 float4 total
        const float4* xs = (const float4*)x + (long)bx * 1024;
        unsigned short* xd = xb + (long)bx * 4096;
#pragma unroll
        for (int i = 0; i < 4; i++) {
            float4 v = xs[i * 256 + t];
            ushort4 o;
            o.x = f2bf(v.x); o.y = f2bf(v.y); o.z = f2bf(v.z); o.w = f2bf(v.w);
            *(ushort4*)(xd + (i * 256 + t) * 4) = o;
        }
        return;
    }
    int wi = bx - 1024;
    int wsel = wi >> 8;                 // 0..3 = q,k,v,o
    int tile = wi & 255;
    int k0 = (tile >> 4) * 64, c0 = (tile & 15) * 64;
    const float* w = (wsel == 0) ? wq : (wsel == 1) ? wk : (wsel == 2) ? wv : wo;
    int lr = t >> 6, lc = t & 63;
#pragma unroll
    for (int rr = 0; rr < 16; rr++) {
        int row = rr * 4 + lr;
        Ts[row][lc] = f2bf(w[(long)(k0 + row) * DM + c0 + lc]);
    }
    __syncthreads();
    unsigned short* dst = (wsel == 3) ? wot : (wqkvt + (long)wsel * DM * DM);
#pragma unroll
    for (int rr = 0; rr < 16; rr++) {
        int crow = rr * 4 + lr;
        dst[(long)(c0 + crow) * DM + k0 + lc] = Ts[lc][crow];
    }
}

// ---------------------------------------------------------------------------
// m97-style 128x128 GEMM core. A [M][1024], Bt [N][1024] both bf16 row-major.
// 256 threads = 4 waves (2x2), wave tile 64x64 = 4x4 MFMA frags.
// BK=32, global_load_lds width 16, 2-barrier K-loop.
// ---------------------------------------------------------------------------
static __device__ __forceinline__ void gemm_tile_128(
    const unsigned short* __restrict__ A, const unsigned short* __restrict__ Bt,
    int m0, int n0, unsigned short* As, unsigned short* Bs, f32x4 (&acc)[4][4])
{
    int t = threadIdx.x;
    int lane = t & 63;
    int wave = t >> 6;
    int l16 = lane & 15, quad = lane >> 4;
    int wm = wave >> 1, wn = wave & 1;

    int off0 = t * 16;          // byte offset in 8KB tile (= wave*1024 + lane*16)
    int off1 = off0 + 4096;
    const char* ga0 = (const char*)(A + (long)(m0 + (off0 >> 6)) * DM) + (off0 & 63);
    const char* ga1 = (const char*)(A + (long)(m0 + (off1 >> 6)) * DM) + (off1 & 63);
    const char* gb0 = (const char*)(Bt + (long)(n0 + (off0 >> 6)) * DM) + (off0 & 63);
    const char* gb1 = (const char*)(Bt + (long)(n0 + (off1 >> 6)) * DM) + (off1 & 63);
    char* sa0 = (char*)As + off0;
    char* sa1 = (char*)As + off1;
    char* sb0 = (char*)Bs + off0;
    char* sb1 = (char*)Bs + off1;

    const unsigned short* fa = As + (wm * 64 + l16) * 32 + quad * 8;
    const unsigned short* fb = Bs + (wn * 64 + l16) * 32 + quad * 8;

    for (int kk = 0; kk < DM; kk += 32) {
        load16_lds(ga0 + kk * 2, sa0);
        load16_lds(ga1 + kk * 2, sa1);
        load16_lds(gb0 + kk * 2, sb0);
        load16_lds(gb1 + kk * 2, sb1);
        __syncthreads();
        bf16x8 af[4], bf[4];
#pragma unroll
        for (int r = 0; r < 4; r++) af[r] = *(const bf16x8*)(fa + r * 16 * 32);
#pragma unroll
        for (int c = 0; c < 4; c++) bf[c] = *(const bf16x8*)(fb + c * 16 * 32);
#pragma unroll
        for (int r = 0; r < 4; r++)
#pragma unroll
            for (int c = 0; c < 4; c++)
                acc[r][c] = __builtin_amdgcn_mfma_f32_16x16x32_bf16(af[r], bf[c], acc[r][c], 0, 0, 0);
        __syncthreads();
    }
}

// ---------------------------------------------------------------------------
// Fused QKV GEMM: N=3072 (z = n0>>10 selects Q/K/V). Q,K stored [bh][n][hd];
// V stored transposed [bh][hd][n] via per-wave LDS transpose (coalesced 8B).
// ---------------------------------------------------------------------------
__global__ __launch_bounds__(256) void qkv_gemm_kernel(
    const unsigned short* __restrict__ A,
    const unsigned short* __restrict__ Bt,
    unsigned short* __restrict__ Qo, unsigned short* __restrict__ Ko,
    unsigned short* __restrict__ Vt)
{
    __shared__ unsigned short As[128 * 32];
    __shared__ unsigned short Bs[128 * 32];
    __shared__ unsigned short Tw[4][16][72];

    f32x4 acc[4][4] = {};
    int m0 = blockIdx.y * 128, n0 = blockIdx.x * 128;
    gemm_tile_128(A, Bt, m0, n0, As, Bs, acc);

    int t = threadIdx.x, wave = t >> 6, lane = t & 63;
    int l16 = lane & 15, quad = lane >> 4;
    int wm = wave >> 1, wn = wave & 1;
    int rg0 = m0 + wm * 64;
    int cg0 = n0 + wn * 64;
    int z = cg0 >> 10;
    int b_ = rg0 >> 11;
    int nb0 = rg0 & (NSEQ - 1);
    int h = (cg0 & 1023) >> 6;
    long bh = (long)(b_ * NH + h);

    if (z < 2) {
        unsigned short* dst = (z == 0 ? Qo : Ko) + bh * NSEQ * HDIM;
#pragma unroll
        for (int r = 0; r < 4; r++)
#pragma unroll
            for (int reg = 0; reg < 4; reg++) {
                long rowb = (long)(nb0 + r * 16 + quad * 4 + reg) * HDIM;
#pragma unroll
                for (int c = 0; c < 4; c++)
                    dst[rowb + c * 16 + l16] = f2bf(acc[r][c][reg]);
            }
    } else {
        unsigned short* dst = Vt + bh * HDIM * NSEQ;
#pragma unroll
        for (int c = 0; c < 4; c++) {
#pragma unroll
            for (int r = 0; r < 4; r++) {
                ushort4 u;
                u.x = f2bf(acc[r][c][0]); u.y = f2bf(acc[r][c][1]);
                u.z = f2bf(acc[r][c][2]); u.w = f2bf(acc[r][c][3]);
                *(ushort4*)&Tw[wave][l16][r * 16 + quad * 4] = u;   // [hd][n]
            }
#pragma unroll
            for (int j = 0; j < 4; j++) {
                int lrow = j * 4 + quad;
                ushort4 u = *(const ushort4*)&Tw[wave][lrow][l16 * 4];
                *(ushort4*)(dst + (long)(c * 16 + lrow) * NSEQ + nb0 + l16 * 4) = u;
            }
        }
    }
}

// ---------------------------------------------------------------------------
// Flash attention, ALiBi + causal. 4 independent waves / 256-thread block,
// 16 queries/wave, 64-key chunks, wave-private LDS P buffer => NO barriers.
// ---------------------------------------------------------------------------
__global__ __launch_bounds__(256) void attn_kernel(
    const unsigned short* __restrict__ Q,
    const unsigned short* __restrict__ K,
    const unsigned short* __restrict__ Vt,
    unsigned short* __restrict__ ctx)
{
    __shared__ unsigned short Pl[4][16][72];
    int t = threadIdx.x, w = t >> 6, lane = t & 63;
    int l16 = lane & 15, quad = lane >> 4;
    int bh = blockIdx.y;
    int b_ = bh >> 4, h = bh & 15;
    int qb = (blockIdx.x * 4 + w) * 16;
    float slope = exp2f(-0.5f * (float)(h + 1));
    const float scale = 0.125f;     // 1/sqrt(64)
    float ss = slope * scale;

    const unsigned short* qp = Q + ((long)bh * NSEQ + qb + l16) * HDIM + quad * 8;
    bf16x8 aq0 = *(const bf16x8*)qp;
    bf16x8 aq1 = *(const bf16x8*)(qp + 32);

    float m_r[4], l_r[4];
    f32x4 o[4] = {};
#pragma unroll
    for (int r = 0; r < 4; r++) { m_r[r] = -1e30f; l_r[r] = 0.0f; }

    int qEnd = qb + 15;
    for (int kb = 0; kb <= qEnd; kb += 64) {
        f32x4 s[4];
        const unsigned short* kp = K + ((long)bh * NSEQ + kb + l16) * HDIM + quad * 8;
#pragma unroll
        for (int tt = 0; tt < 4; tt++) {
            bf16x8 k0 = *(const bf16x8*)(kp + tt * 16 * HDIM);
            bf16x8 k1 = *(const bf16x8*)(kp + tt * 16 * HDIM + 32);
            f32x4 z = {};
            z = __builtin_amdgcn_mfma_f32_16x16x32_bf16(aq0, k0, z, 0, 0, 0);
            s[tt] = __builtin_amdgcn_mfma_f32_16x16x32_bf16(aq1, k1, z, 0, 0, 0);
        }
        float p[4][4];
#pragma unroll
        for (int r = 0; r < 4; r++) {
            int i = qb + quad * 4 + r;
            float fd0 = (float)(i - kb - l16);
            float mv = -1e30f;
#pragma unroll
            for (int tt = 0; tt < 4; tt++) {
                float dist = fd0 - 16.0f * tt;
                float v = (dist >= 0.f) ? (s[tt][r] * scale - ss * dist) : -1e30f;
                p[r][tt] = v;
                mv = fmaxf(mv, v);
            }
            mv = fmaxf(mv, __shfl_xor(mv, 1));
            mv = fmaxf(mv, __shfl_xor(mv, 2));
            mv = fmaxf(mv, __shfl_xor(mv, 4));
            mv = fmaxf(mv, __shfl_xor(mv, 8));
            float mnew = fmaxf(m_r[r], mv);
            float alpha = __expf(m_r[r] - mnew);
            m_r[r] = mnew;
            float sum = 0.f;
#pragma unroll
            for (int tt = 0; tt < 4; tt++) {
                float e = __expf(p[r][tt] - mnew);
                p[r][tt] = e;
                sum += e;
            }
            sum += __shfl_xor(sum, 1);
            sum += __shfl_xor(sum, 2);
            sum += __shfl_xor(sum, 4);
            sum += __shfl_xor(sum, 8);
            l_r[r] = l_r[r] * alpha + sum;
#pragma unroll
            for (int cb = 0; cb < 4; cb++) o[cb][r] *= alpha;
        }
#pragma unroll
        for (int r = 0; r < 4; r++)
#pragma unroll
            for (int tt = 0; tt < 4; tt++)
                Pl[w][quad * 4 + r][tt * 16 + l16] = f2bf(p[r][tt]);
        bf16x8 ap0 = *(const bf16x8*)&Pl[w][l16][quad * 8];
        bf16x8 ap1 = *(const bf16x8*)&Pl[w][l16][32 + quad * 8];
        const unsigned short* vp = Vt + ((long)bh * HDIM + l16) * NSEQ + kb + quad * 8;
#pragma unroll
        for (int cb = 0; cb < 4; cb++) {
            bf16x8 v0 = *(const bf16x8*)(vp + (long)cb * 16 * NSEQ);
            bf16x8 v1 = *(const bf16x8*)(vp + (long)cb * 16 * NSEQ + 32);
            o[cb] = __builtin_amdgcn_mfma_f32_16x16x32_bf16(ap0, v0, o[cb], 0, 0, 0);
            o[cb] = __builtin_amdgcn_mfma_f32_16x16x32_bf16(ap1, v1, o[cb], 0, 0, 0);
        }
    }
#pragma unroll
    for (int r = 0; r < 4; r++) {
        float inv = 1.0f / l_r[r];
        int n_ = qb + quad * 4 + r;
        long base = (((long)b_ * NSEQ + n_) * NH + h) * HDIM;
#pragma unroll
        for (int cb = 0; cb < 4; cb++)
            ctx[base + cb * 16 + l16] = f2bf(o[cb][r] * inv);
    }
}

// ---------------------------------------------------------------------------
// Output projection: out = ctx[4096x1024] @ Wo + bo, fp32 out.
// ---------------------------------------------------------------------------
__global__ __launch_bounds__(256) void out_gemm_kernel(
    const unsigned short* __restrict__ A,
    const unsigned short* __restrict__ Bt,
    const float* __restrict__ bias,
    float* __restrict__ out)
{
    __shared__ unsigned short As[128 * 32];
    __shared__ unsigned short Bs[128 * 32];
    f32x4 acc[4][4] = {};
    int m0 = blockIdx.y * 128, n0 = blockIdx.x * 128;
    gemm_tile_128(A, Bt, m0, n0, As, Bs, acc);

    int t = threadIdx.x, wave = t >> 6, lane = t & 63;
    int l16 = lane & 15, quad = lane >> 4;
    int wm = wave >> 1, wn = wave & 1;
    int rg0 = m0 + wm * 64, cg0 = n0 + wn * 64;
#pragma unroll
    for (int c = 0; c < 4; c++) {
        float bc = bias[cg0 + c * 16 + l16];
#pragma unroll
        for (int r = 0; r < 4; r++)
#pragma unroll
            for (int reg = 0; reg < 4; reg++)
                out[(long)(rg0 + r * 16 + quad * 4 + reg) * DM + cg0 + c * 16 + l16] =
                    acc[r][c][reg] + bc;
    }
}

// ---------------------------------------------------------------------------
extern "C" void kernel_launch(void* const* d_in, const int* in_sizes, int n_in,
                              void* d_out, int out_size, void* d_ws, size_t ws_size,
                              hipStream_t stream)
{
    const float* x  = (const float*)d_in[0];
    const float* wq = (const float*)d_in[1];
    const float* wk = (const float*)d_in[2];
    const float* wv = (const float*)d_in[3];
    const float* wo = (const float*)d_in[4];
    const float* bo = (const float*)d_in[5];

    char* ws = (char*)d_ws;
    unsigned short* xb    = (unsigned short*)(ws);                 // 8 MiB
    unsigned short* wqkvt = (unsigned short*)(ws + (8L  << 20));   // 6 MiB [3072][1024]
    unsigned short* wot   = (unsigned short*)(ws + (14L << 20));   // 2 MiB
    unsigned short* Qb    = (unsigned short*)(ws + (16L << 20));   // 8 MiB
    unsigned short* Kb    = (unsigned short*)(ws + (24L << 20));   // 8 MiB
    unsigned short* Vt    = (unsigned short*)(ws + (32L << 20));   // 8 MiB
    unsigned short* ctx   = (unsigned short*)(ws + (40L << 20));   // 8 MiB
    float* out = (float*)d_out;

    convert_kernel<<<2048, 256, 0, stream>>>(x, wq, wk, wv, wo, xb, wqkvt, wot);

    qkv_gemm_kernel<<<dim3(3 * DM / 128, MROWS / 128), 256, 0, stream>>>(
        xb, wqkvt, Qb, Kb, Vt);

    attn_kernel<<<dim3(NSEQ / 64, NB * NH), 256, 0, stream>>>(Qb, Kb, Vt, ctx);

    out_gemm_kernel<<<dim3(DM / 128, MROWS / 128), 256, 0, stream>>>(
        ctx, wot, bo, out);
}

// Round 4
// 277.005 us; speedup vs baseline: 2.2253x; 1.3751x over previous
//
#include <hip/hip_runtime.h>
#include <hip/hip_bf16.h>
#include <stdint.h>

#define NH 16
#define HDIM 64
#define NB 2
#define NSEQ 2048
#define DM 1024
#define MROWS (NB * NSEQ)   // 4096

typedef __attribute__((ext_vector_type(8))) short bf16x8;
typedef __attribute__((ext_vector_type(4))) float f32x4;

static __device__ __forceinline__ unsigned short f2bf(float f) {
    union { float f; unsigned u; } v;
    v.f = f;
    unsigned r = v.u + 0x7fffu + ((v.u >> 16) & 1u);   // RNE
    return (unsigned short)(r >> 16);
}

typedef __attribute__((address_space(1))) void* gas_ptr;
typedef __attribute__((address_space(3))) void* las_ptr;

// async global->LDS, 16B per lane. LDS dest must be wave-uniform base + lane*16.
static __device__ __forceinline__ void load16_lds(const void* g, void* l) {
    __builtin_amdgcn_global_load_lds((gas_ptr)(uintptr_t)g, (las_ptr)(uintptr_t)l,
                                     16, 0, 0);
}

// ---------------------------------------------------------------------------
// Convert: x -> bf16 (blocks 0..1023), weights -> bf16 transposed via LDS
// tile transpose (blocks 1024..2047).
// ---------------------------------------------------------------------------
__global__ __launch_bounds__(256) void convert_kernel(
    const float* __restrict__ x,
    const float* __restrict__ wq, const float* __restrict__ wk,
    const float* __restrict__ wv, const float* __restrict__ wo,
    unsigned short* __restrict__ xb,
    unsigned short* __restrict__ wqkvt,
    unsigned short* __restrict__ wot)
{
    __shared__ unsigned short Ts[64][66];
    int t = threadIdx.x;
    int bx = blockIdx.x;
    if (bx < 1024) {
        const float4* xs = (const float4*)x + (long)bx * 1024;
        unsigned short* xd = xb + (long)bx * 4096;
#pragma unroll
        for (int i = 0; i < 4; i++) {
            float4 v = xs[i * 256 + t];
            ushort4 o;
            o.x = f2bf(v.x); o.y = f2bf(v.y); o.z = f2bf(v.z); o.w = f2bf(v.w);
            *(ushort4*)(xd + (i * 256 + t) * 4) = o;
        }
        return;
    }
    int wi = bx - 1024;
    int wsel = wi >> 8;                 // 0..3 = q,k,v,o
    int tile = wi & 255;
    int k0 = (tile >> 4) * 64, c0 = (tile & 15) * 64;
    const float* w = (wsel == 0) ? wq : (wsel == 1) ? wk : (wsel == 2) ? wv : wo;
    int lr = t >> 6, lc = t & 63;
#pragma unroll
    for (int rr = 0; rr < 16; rr++) {
        int row = rr * 4 + lr;
        Ts[row][lc] = f2bf(w[(long)(k0 + row) * DM + c0 + lc]);
    }
    __syncthreads();
    unsigned short* dst = (wsel == 3) ? wot : (wqkvt + (long)wsel * DM * DM);
#pragma unroll
    for (int rr = 0; rr < 16; rr++) {
        int crow = rr * 4 + lr;
        dst[(long)(c0 + crow) * DM + k0 + lc] = Ts[lc][crow];
    }
}

// ---------------------------------------------------------------------------
// m97-style 128x128 GEMM core (unchanged from round 3).
// ---------------------------------------------------------------------------
static __device__ __forceinline__ void gemm_tile_128(
    const unsigned short* __restrict__ A, const unsigned short* __restrict__ Bt,
    int m0, int n0, unsigned short* As, unsigned short* Bs, f32x4 (&acc)[4][4])
{
    int t = threadIdx.x;
    int lane = t & 63;
    int wave = t >> 6;
    int l16 = lane & 15, quad = lane >> 4;
    int wm = wave >> 1, wn = wave & 1;

    int off0 = t * 16;
    int off1 = off0 + 4096;
    const char* ga0 = (const char*)(A + (long)(m0 + (off0 >> 6)) * DM) + (off0 & 63);
    const char* ga1 = (const char*)(A + (long)(m0 + (off1 >> 6)) * DM) + (off1 & 63);
    const char* gb0 = (const char*)(Bt + (long)(n0 + (off0 >> 6)) * DM) + (off0 & 63);
    const char* gb1 = (const char*)(Bt + (long)(n0 + (off1 >> 6)) * DM) + (off1 & 63);
    char* sa0 = (char*)As + off0;
    char* sa1 = (char*)As + off1;
    char* sb0 = (char*)Bs + off0;
    char* sb1 = (char*)Bs + off1;

    const unsigned short* fa = As + (wm * 64 + l16) * 32 + quad * 8;
    const unsigned short* fb = Bs + (wn * 64 + l16) * 32 + quad * 8;

    for (int kk = 0; kk < DM; kk += 32) {
        load16_lds(ga0 + kk * 2, sa0);
        load16_lds(ga1 + kk * 2, sa1);
        load16_lds(gb0 + kk * 2, sb0);
        load16_lds(gb1 + kk * 2, sb1);
        __syncthreads();
        bf16x8 af[4], bf[4];
#pragma unroll
        for (int r = 0; r < 4; r++) af[r] = *(const bf16x8*)(fa + r * 16 * 32);
#pragma unroll
        for (int c = 0; c < 4; c++) bf[c] = *(const bf16x8*)(fb + c * 16 * 32);
#pragma unroll
        for (int r = 0; r < 4; r++)
#pragma unroll
            for (int c = 0; c < 4; c++)
                acc[r][c] = __builtin_amdgcn_mfma_f32_16x16x32_bf16(af[r], bf[c], acc[r][c], 0, 0, 0);
        __syncthreads();
    }
}

// ---------------------------------------------------------------------------
// Fused QKV GEMM (unchanged from round 3).
// ---------------------------------------------------------------------------
__global__ __launch_bounds__(256) void qkv_gemm_kernel(
    const unsigned short* __restrict__ A,
    const unsigned short* __restrict__ Bt,
    unsigned short* __restrict__ Qo, unsigned short* __restrict__ Ko,
    unsigned short* __restrict__ Vt)
{
    __shared__ unsigned short As[128 * 32];
    __shared__ unsigned short Bs[128 * 32];
    __shared__ unsigned short Tw[4][16][72];

    f32x4 acc[4][4] = {};
    int m0 = blockIdx.y * 128, n0 = blockIdx.x * 128;
    gemm_tile_128(A, Bt, m0, n0, As, Bs, acc);

    int t = threadIdx.x, wave = t >> 6, lane = t & 63;
    int l16 = lane & 15, quad = lane >> 4;
    int wm = wave >> 1, wn = wave & 1;
    int rg0 = m0 + wm * 64;
    int cg0 = n0 + wn * 64;
    int z = cg0 >> 10;
    int b_ = rg0 >> 11;
    int nb0 = rg0 & (NSEQ - 1);
    int h = (cg0 & 1023) >> 6;
    long bh = (long)(b_ * NH + h);

    if (z < 2) {
        unsigned short* dst = (z == 0 ? Qo : Ko) + bh * NSEQ * HDIM;
#pragma unroll
        for (int r = 0; r < 4; r++)
#pragma unroll
            for (int reg = 0; reg < 4; reg++) {
                long rowb = (long)(nb0 + r * 16 + quad * 4 + reg) * HDIM;
#pragma unroll
                for (int c = 0; c < 4; c++)
                    dst[rowb + c * 16 + l16] = f2bf(acc[r][c][reg]);
            }
    } else {
        unsigned short* dst = Vt + bh * HDIM * NSEQ;
#pragma unroll
        for (int c = 0; c < 4; c++) {
#pragma unroll
            for (int r = 0; r < 4; r++) {
                ushort4 u;
                u.x = f2bf(acc[r][c][0]); u.y = f2bf(acc[r][c][1]);
                u.z = f2bf(acc[r][c][2]); u.w = f2bf(acc[r][c][3]);
                *(ushort4*)&Tw[wave][l16][r * 16 + quad * 4] = u;   // [hd][n]
            }
#pragma unroll
            for (int j = 0; j < 4; j++) {
                int lrow = j * 4 + quad;
                ushort4 u = *(const ushort4*)&Tw[wave][lrow][l16 * 4];
                *(ushort4*)(dst + (long)(c * 16 + lrow) * NSEQ + nb0 + l16 * 4) = u;
            }
        }
    }
}

// ---------------------------------------------------------------------------
// Flash attention v2: one block = one 64-query tile (4 waves x 16q), shared
// double-buffered LDS K/V staging via global_load_lds with XOR-swizzled
// layout (block = row*8 + (seg ^ (row&7)), 16B blocks) to kill bank
// conflicts. One barrier per 64-key chunk; stage of chunk c+1 overlaps
// compute of chunk c. tile = 31-blockIdx.x so the big tiles start first.
// ---------------------------------------------------------------------------
static __device__ __forceinline__ void stage_kv(
    const unsigned short* __restrict__ Kg,
    const unsigned short* __restrict__ Vtg,
    int kb, unsigned short* buf, int t)
{
#pragma unroll
    for (int r = 0; r < 2; r++) {
        int b = r * 256 + t;
        int row = b >> 3, sp = b & 7;
        int s = sp ^ (row & 7);
        load16_lds(Kg + (long)(kb + row) * HDIM + s * 8, buf + b * 8);
    }
#pragma unroll
    for (int r = 0; r < 2; r++) {
        int b = r * 256 + t;
        int row = b >> 3, sp = b & 7;
        int s = sp ^ (row & 7);
        load16_lds(Vtg + (long)row * NSEQ + kb + s * 8, buf + 4096 + b * 8);
    }
}

__global__ __launch_bounds__(256) void attn_kernel(
    const unsigned short* __restrict__ Q,
    const unsigned short* __restrict__ K,
    const unsigned short* __restrict__ Vt,
    unsigned short* __restrict__ ctx)
{
    __shared__ unsigned short KV[2][8192];   // [buf][K:4096 | V:4096]
    __shared__ unsigned short Pl[4][16][72];

    int t = threadIdx.x, w = t >> 6, lane = t & 63;
    int l16 = lane & 15, quad = lane >> 4;
    int r7 = l16 & 7;
    int bh = blockIdx.y;
    int b_ = bh >> 4, h = bh & 15;
    int tile = gridDim.x - 1 - blockIdx.x;   // big tiles dispatch first
    int q0 = tile * 64;
    int qb = q0 + w * 16;
    int nch = tile + 1;

    const unsigned short* Kg  = K  + (long)bh * NSEQ * HDIM;
    const unsigned short* Vtg = Vt + (long)bh * HDIM * NSEQ;

    float slope = exp2f(-0.5f * (float)(h + 1));
    const float scale = 0.125f;     // 1/sqrt(64)
    float ss = slope * scale;

    const unsigned short* qp = Q + ((long)bh * NSEQ + qb + l16) * HDIM + quad * 8;
    bf16x8 aq0 = *(const bf16x8*)qp;
    bf16x8 aq1 = *(const bf16x8*)(qp + 32);

    float m_r[4], l_r[4];
    f32x4 o[4] = {};
#pragma unroll
    for (int r = 0; r < 4; r++) { m_r[r] = -1e30f; l_r[r] = 0.0f; }

    stage_kv(Kg, Vtg, 0, KV[0], t);

    for (int c = 0; c < nch; c++) {
        __syncthreads();
        if (c + 1 < nch) stage_kv(Kg, Vtg, (c + 1) * 64, KV[(c + 1) & 1], t);

        const unsigned short* Ks = KV[c & 1];
        const unsigned short* Vs = KV[c & 1] + 4096;
        int kb = c * 64;
        bool last = (c == nch - 1);

        // ---- S = Q K^T, 16 q x 64 keys
        f32x4 s[4];
#pragma unroll
        for (int tt = 0; tt < 4; tt++) {
            int rr = tt * 16 + l16;
            bf16x8 k0 = *(const bf16x8*)(Ks + (rr * 8 + (quad ^ r7)) * 8);
            bf16x8 k1 = *(const bf16x8*)(Ks + (rr * 8 + ((quad + 4) ^ r7)) * 8);
            f32x4 z = {};
            z = __builtin_amdgcn_mfma_f32_16x16x32_bf16(aq0, k0, z, 0, 0, 0);
            s[tt] = __builtin_amdgcn_mfma_f32_16x16x32_bf16(aq1, k1, z, 0, 0, 0);
        }

        // ---- alibi (+ causal mask on diagonal chunk), online softmax
        float p[4][4];
#pragma unroll
        for (int r = 0; r < 4; r++) {
            int i = qb + quad * 4 + r;
            float fd0 = (float)(i - kb - l16);
            float mv = -1e30f;
#pragma unroll
            for (int tt = 0; tt < 4; tt++) {
                float dist = fd0 - 16.0f * tt;
                float v = s[tt][r] * scale - ss * dist;
                if (last && dist < 0.f) v = -1e30f;
                p[r][tt] = v;
                mv = fmaxf(mv, v);
            }
            mv = fmaxf(mv, __shfl_xor(mv, 1));
            mv = fmaxf(mv, __shfl_xor(mv, 2));
            mv = fmaxf(mv, __shfl_xor(mv, 4));
            mv = fmaxf(mv, __shfl_xor(mv, 8));
            float mnew = fmaxf(m_r[r], mv);
            float alpha = __expf(m_r[r] - mnew);
            m_r[r] = mnew;
            float sum = 0.f;
#pragma unroll
            for (int tt = 0; tt < 4; tt++) {
                float e = __expf(p[r][tt] - mnew);
                p[r][tt] = e;
                sum += e;
            }
            sum += __shfl_xor(sum, 1);
            sum += __shfl_xor(sum, 2);
            sum += __shfl_xor(sum, 4);
            sum += __shfl_xor(sum, 8);
            l_r[r] = l_r[r] * alpha + sum;
#pragma unroll
            for (int cb = 0; cb < 4; cb++) o[cb][r] *= alpha;
        }

        // ---- P: C-layout -> LDS -> A-layout
#pragma unroll
        for (int r = 0; r < 4; r++)
#pragma unroll
            for (int tt = 0; tt < 4; tt++)
                Pl[w][quad * 4 + r][tt * 16 + l16] = f2bf(p[r][tt]);
        bf16x8 ap0 = *(const bf16x8*)&Pl[w][l16][quad * 8];
        bf16x8 ap1 = *(const bf16x8*)&Pl[w][l16][32 + quad * 8];

        // ---- O += P V from swizzled Vs
#pragma unroll
        for (int cb = 0; cb < 4; cb++) {
            int rr = cb * 16 + l16;
            bf16x8 v0 = *(const bf16x8*)(Vs + (rr * 8 + (quad ^ r7)) * 8);
            bf16x8 v1 = *(const bf16x8*)(Vs + (rr * 8 + ((quad + 4) ^ r7)) * 8);
            o[cb] = __builtin_amdgcn_mfma_f32_16x16x32_bf16(ap0, v0, o[cb], 0, 0, 0);
            o[cb] = __builtin_amdgcn_mfma_f32_16x16x32_bf16(ap1, v1, o[cb], 0, 0, 0);
        }
    }

    // ---- normalize, store ctx [b, n, h, hd]
#pragma unroll
    for (int r = 0; r < 4; r++) {
        float inv = 1.0f / l_r[r];
        int n_ = qb + quad * 4 + r;
        long base = (((long)b_ * NSEQ + n_) * NH + h) * HDIM;
#pragma unroll
        for (int cb = 0; cb < 4; cb++)
            ctx[base + cb * 16 + l16] = f2bf(o[cb][r] * inv);
    }
}

// ---------------------------------------------------------------------------
// Output projection (unchanged from round 3).
// ---------------------------------------------------------------------------
__global__ __launch_bounds__(256) void out_gemm_kernel(
    const unsigned short* __restrict__ A,
    const unsigned short* __restrict__ Bt,
    const float* __restrict__ bias,
    float* __restrict__ out)
{
    __shared__ unsigned short As[128 * 32];
    __shared__ unsigned short Bs[128 * 32];
    f32x4 acc[4][4] = {};
    int m0 = blockIdx.y * 128, n0 = blockIdx.x * 128;
    gemm_tile_128(A, Bt, m0, n0, As, Bs, acc);

    int t = threadIdx.x, wave = t >> 6, lane = t & 63;
    int l16 = lane & 15, quad = lane >> 4;
    int wm = wave >> 1, wn = wave & 1;
    int rg0 = m0 + wm * 64, cg0 = n0 + wn * 64;
#pragma unroll
    for (int c = 0; c < 4; c++) {
        float bc = bias[cg0 + c * 16 + l16];
#pragma unroll
        for (int r = 0; r < 4; r++)
#pragma unroll
            for (int reg = 0; reg < 4; reg++)
                out[(long)(rg0 + r * 16 + quad * 4 + reg) * DM + cg0 + c * 16 + l16] =
                    acc[r][c][reg] + bc;
    }
}

// ---------------------------------------------------------------------------
extern "C" void kernel_launch(void* const* d_in, const int* in_sizes, int n_in,
                              void* d_out, int out_size, void* d_ws, size_t ws_size,
                              hipStream_t stream)
{
    const float* x  = (const float*)d_in[0];
    const float* wq = (const float*)d_in[1];
    const float* wk = (const float*)d_in[2];
    const float* wv = (const float*)d_in[3];
    const float* wo = (const float*)d_in[4];
    const float* bo = (const float*)d_in[5];

    char* ws = (char*)d_ws;
    unsigned short* xb    = (unsigned short*)(ws);                 // 8 MiB
    unsigned short* wqkvt = (unsigned short*)(ws + (8L  << 20));   // 6 MiB [3072][1024]
    unsigned short* wot   = (unsigned short*)(ws + (14L << 20));   // 2 MiB
    unsigned short* Qb    = (unsigned short*)(ws + (16L << 20));   // 8 MiB
    unsigned short* Kb    = (unsigned short*)(ws + (24L << 20));   // 8 MiB
    unsigned short* Vt    = (unsigned short*)(ws + (32L << 20));   // 8 MiB
    unsigned short* ctx   = (unsigned short*)(ws + (40L << 20));   // 8 MiB
    float* out = (float*)d_out;

    convert_kernel<<<2048, 256, 0, stream>>>(x, wq, wk, wv, wo, xb, wqkvt, wot);

    qkv_gemm_kernel<<<dim3(3 * DM / 128, MROWS / 128), 256, 0, stream>>>(
        xb, wqkvt, Qb, Kb, Vt);

    attn_kernel<<<dim3(NSEQ / 64, NB * NH), 256, 0, stream>>>(Qb, Kb, Vt, ctx);

    out_gemm_kernel<<<dim3(DM / 128, MROWS / 128), 256, 0, stream>>>(
        ctx, wot, bo, out);
}

// Round 5
// 226.737 us; speedup vs baseline: 2.7186x; 1.2217x over previous
//
#include <hip/hip_runtime.h>
#include <hip/hip_bf16.h>
#include <stdint.h>

#define NH 16
#define HDIM 64
#define NB 2
#define NSEQ 2048
#define DM 1024
#define MROWS (NB * NSEQ)   // 4096

typedef __attribute__((ext_vector_type(8))) short bf16x8;
typedef __attribute__((ext_vector_type(4))) float f32x4;

static __device__ __forceinline__ unsigned short f2bf(float f) {
    union { float f; unsigned u; } v;
    v.f = f;
    unsigned r = v.u + 0x7fffu + ((v.u >> 16) & 1u);   // RNE
    return (unsigned short)(r >> 16);
}

static __device__ __forceinline__ float fexp2(float x) {
#if __has_builtin(__builtin_amdgcn_exp2f)
    return __builtin_amdgcn_exp2f(x);
#else
    return exp2f(x);
#endif
}

typedef __attribute__((address_space(1))) void* gas_ptr;
typedef __attribute__((address_space(3))) void* las_ptr;

// async global->LDS, 16B per lane. LDS dest must be wave-uniform base + lane*16.
static __device__ __forceinline__ void load16_lds(const void* g, void* l) {
    __builtin_amdgcn_global_load_lds((gas_ptr)(uintptr_t)g, (las_ptr)(uintptr_t)l,
                                     16, 0, 0);
}

// ---------------------------------------------------------------------------
// Convert: x -> bf16 (blocks 0..1023), weights -> bf16 transposed via LDS
// tile transpose (blocks 1024..2047).
// ---------------------------------------------------------------------------
__global__ __launch_bounds__(256) void convert_kernel(
    const float* __restrict__ x,
    const float* __restrict__ wq, const float* __restrict__ wk,
    const float* __restrict__ wv, const float* __restrict__ wo,
    unsigned short* __restrict__ xb,
    unsigned short* __restrict__ wqkvt,
    unsigned short* __restrict__ wot)
{
    __shared__ unsigned short Ts[64][66];
    int t = threadIdx.x;
    int bx = blockIdx.x;
    if (bx < 1024) {
        const float4* xs = (const float4*)x + (long)bx * 1024;
        unsigned short* xd = xb + (long)bx * 4096;
#pragma unroll
        for (int i = 0; i < 4; i++) {
            float4 v = xs[i * 256 + t];
            ushort4 o;
            o.x = f2bf(v.x); o.y = f2bf(v.y); o.z = f2bf(v.z); o.w = f2bf(v.w);
            *(ushort4*)(xd + (i * 256 + t) * 4) = o;
        }
        return;
    }
    int wi = bx - 1024;
    int wsel = wi >> 8;                 // 0..3 = q,k,v,o
    int tile = wi & 255;
    int k0 = (tile >> 4) * 64, c0 = (tile & 15) * 64;
    const float* w = (wsel == 0) ? wq : (wsel == 1) ? wk : (wsel == 2) ? wv : wo;
    int lr = t >> 6, lc = t & 63;
#pragma unroll
    for (int rr = 0; rr < 16; rr++) {
        int row = rr * 4 + lr;
        Ts[row][lc] = f2bf(w[(long)(k0 + row) * DM + c0 + lc]);
    }
    __syncthreads();
    unsigned short* dst = (wsel == 3) ? wot : (wqkvt + (long)wsel * DM * DM);
#pragma unroll
    for (int rr = 0; rr < 16; rr++) {
        int crow = rr * 4 + lr;
        dst[(long)(c0 + crow) * DM + k0 + lc] = Ts[lc][crow];
    }
}

// ---------------------------------------------------------------------------
// m97-style 128x128 GEMM core (unchanged).
// ---------------------------------------------------------------------------
static __device__ __forceinline__ void gemm_tile_128(
    const unsigned short* __restrict__ A, const unsigned short* __restrict__ Bt,
    int m0, int n0, unsigned short* As, unsigned short* Bs, f32x4 (&acc)[4][4])
{
    int t = threadIdx.x;
    int lane = t & 63;
    int wave = t >> 6;
    int l16 = lane & 15, quad = lane >> 4;
    int wm = wave >> 1, wn = wave & 1;

    int off0 = t * 16;
    int off1 = off0 + 4096;
    const char* ga0 = (const char*)(A + (long)(m0 + (off0 >> 6)) * DM) + (off0 & 63);
    const char* ga1 = (const char*)(A + (long)(m0 + (off1 >> 6)) * DM) + (off1 & 63);
    const char* gb0 = (const char*)(Bt + (long)(n0 + (off0 >> 6)) * DM) + (off0 & 63);
    const char* gb1 = (const char*)(Bt + (long)(n0 + (off1 >> 6)) * DM) + (off1 & 63);
    char* sa0 = (char*)As + off0;
    char* sa1 = (char*)As + off1;
    char* sb0 = (char*)Bs + off0;
    char* sb1 = (char*)Bs + off1;

    const unsigned short* fa = As + (wm * 64 + l16) * 32 + quad * 8;
    const unsigned short* fb = Bs + (wn * 64 + l16) * 32 + quad * 8;

    for (int kk = 0; kk < DM; kk += 32) {
        load16_lds(ga0 + kk * 2, sa0);
        load16_lds(ga1 + kk * 2, sa1);
        load16_lds(gb0 + kk * 2, sb0);
        load16_lds(gb1 + kk * 2, sb1);
        __syncthreads();
        bf16x8 af[4], bf[4];
#pragma unroll
        for (int r = 0; r < 4; r++) af[r] = *(const bf16x8*)(fa + r * 16 * 32);
#pragma unroll
        for (int c = 0; c < 4; c++) bf[c] = *(const bf16x8*)(fb + c * 16 * 32);
#pragma unroll
        for (int r = 0; r < 4; r++)
#pragma unroll
            for (int c = 0; c < 4; c++)
                acc[r][c] = __builtin_amdgcn_mfma_f32_16x16x32_bf16(af[r], bf[c], acc[r][c], 0, 0, 0);
        __syncthreads();
    }
}

// ---------------------------------------------------------------------------
// Fused QKV GEMM (unchanged).
// ---------------------------------------------------------------------------
__global__ __launch_bounds__(256) void qkv_gemm_kernel(
    const unsigned short* __restrict__ A,
    const unsigned short* __restrict__ Bt,
    unsigned short* __restrict__ Qo, unsigned short* __restrict__ Ko,
    unsigned short* __restrict__ Vt)
{
    __shared__ unsigned short As[128 * 32];
    __shared__ unsigned short Bs[128 * 32];
    __shared__ unsigned short Tw[4][16][72];

    f32x4 acc[4][4] = {};
    int m0 = blockIdx.y * 128, n0 = blockIdx.x * 128;
    gemm_tile_128(A, Bt, m0, n0, As, Bs, acc);

    int t = threadIdx.x, wave = t >> 6, lane = t & 63;
    int l16 = lane & 15, quad = lane >> 4;
    int wm = wave >> 1, wn = wave & 1;
    int rg0 = m0 + wm * 64;
    int cg0 = n0 + wn * 64;
    int z = cg0 >> 10;
    int b_ = rg0 >> 11;
    int nb0 = rg0 & (NSEQ - 1);
    int h = (cg0 & 1023) >> 6;
    long bh = (long)(b_ * NH + h);

    if (z < 2) {
        unsigned short* dst = (z == 0 ? Qo : Ko) + bh * NSEQ * HDIM;
#pragma unroll
        for (int r = 0; r < 4; r++)
#pragma unroll
            for (int reg = 0; reg < 4; reg++) {
                long rowb = (long)(nb0 + r * 16 + quad * 4 + reg) * HDIM;
#pragma unroll
                for (int c = 0; c < 4; c++)
                    dst[rowb + c * 16 + l16] = f2bf(acc[r][c][reg]);
            }
    } else {
        unsigned short* dst = Vt + bh * HDIM * NSEQ;
#pragma unroll
        for (int c = 0; c < 4; c++) {
#pragma unroll
            for (int r = 0; r < 4; r++) {
                ushort4 u;
                u.x = f2bf(acc[r][c][0]); u.y = f2bf(acc[r][c][1]);
                u.z = f2bf(acc[r][c][2]); u.w = f2bf(acc[r][c][3]);
                *(ushort4*)&Tw[wave][l16][r * 16 + quad * 4] = u;   // [hd][n]
            }
#pragma unroll
            for (int j = 0; j < 4; j++) {
                int lrow = j * 4 + quad;
                ushort4 u = *(const ushort4*)&Tw[wave][lrow][l16 * 4];
                *(ushort4*)(dst + (long)(c * 16 + lrow) * NSEQ + nb0 + l16 * 4) = u;
            }
        }
    }
}

// ---------------------------------------------------------------------------
// Flash attention v3: triangle-balanced pair fusion. Block p (0..15) owns
// q-tiles t1=31-p and t0=p of one head, processing BOTH against one shared
// K/V chunk stream (t0's chunks are a prefix of t1's). Work per block =
// (32-p)+(p+1) = 33 chunk-units, uniform => 512 equal blocks, 2/CU, no tail.
// exp2-domain online softmax. XOR-swizzled LDS K/V staging (round 4).
// ---------------------------------------------------------------------------
static __device__ __forceinline__ void stage_kv(
    const unsigned short* __restrict__ Kg,
    const unsigned short* __restrict__ Vtg,
    int kb, unsigned short* buf, int t)
{
#pragma unroll
    for (int r = 0; r < 2; r++) {
        int b = r * 256 + t;
        int row = b >> 3, sp = b & 7;
        int s = sp ^ (row & 7);
        load16_lds(Kg + (long)(kb + row) * HDIM + s * 8, buf + b * 8);
    }
#pragma unroll
    for (int r = 0; r < 2; r++) {
        int b = r * 256 + t;
        int row = b >> 3, sp = b & 7;
        int s = sp ^ (row & 7);
        load16_lds(Vtg + (long)row * NSEQ + kb + s * 8, buf + 4096 + b * 8);
    }
}

static __device__ __forceinline__ void attn_chunk(
    const bf16x8& aq0, const bf16x8& aq1,
    const unsigned short* __restrict__ Ks, const unsigned short* __restrict__ Vs,
    int kb, int qb, bool last, float sc2, float ss2,
    float* m_r, float* l_r, f32x4* o,
    unsigned short* PlW, int l16, int quad, int r7)
{
    // ---- S = Q K^T, 16 q x 64 keys (swizzled LDS reads)
    f32x4 s[4];
#pragma unroll
    for (int tt = 0; tt < 4; tt++) {
        int rr = tt * 16 + l16;
        bf16x8 k0 = *(const bf16x8*)(Ks + (rr * 8 + (quad ^ r7)) * 8);
        bf16x8 k1 = *(const bf16x8*)(Ks + (rr * 8 + ((quad + 4) ^ r7)) * 8);
        f32x4 z = {};
        z = __builtin_amdgcn_mfma_f32_16x16x32_bf16(aq0, k0, z, 0, 0, 0);
        s[tt] = __builtin_amdgcn_mfma_f32_16x16x32_bf16(aq1, k1, z, 0, 0, 0);
    }

    // ---- alibi (+ causal mask on own diagonal chunk), exp2-domain softmax
    float p[4][4];
#pragma unroll
    for (int r = 0; r < 4; r++) {
        int i = qb + quad * 4 + r;
        float fd0 = (float)(i - kb - l16);
        float mv = -3e38f;
#pragma unroll
        for (int tt = 0; tt < 4; tt++) {
            float dist = fd0 - 16.0f * tt;
            float v = s[tt][r] * sc2 - ss2 * dist;
            if (last && dist < 0.f) v = -3e38f;
            p[r][tt] = v;
            mv = fmaxf(mv, v);
        }
        mv = fmaxf(mv, __shfl_xor(mv, 1));
        mv = fmaxf(mv, __shfl_xor(mv, 2));
        mv = fmaxf(mv, __shfl_xor(mv, 4));
        mv = fmaxf(mv, __shfl_xor(mv, 8));
        float mnew = fmaxf(m_r[r], mv);
        float alpha = fexp2(m_r[r] - mnew);
        m_r[r] = mnew;
        float sum = 0.f;
#pragma unroll
        for (int tt = 0; tt < 4; tt++) {
            float e = fexp2(p[r][tt] - mnew);
            p[r][tt] = e;
            sum += e;
        }
        sum += __shfl_xor(sum, 1);
        sum += __shfl_xor(sum, 2);
        sum += __shfl_xor(sum, 4);
        sum += __shfl_xor(sum, 8);
        l_r[r] = l_r[r] * alpha + sum;
#pragma unroll
        for (int cb = 0; cb < 4; cb++) o[cb][r] *= alpha;
    }

    // ---- P: C-layout -> LDS -> A-layout
#pragma unroll
    for (int r = 0; r < 4; r++)
#pragma unroll
        for (int tt = 0; tt < 4; tt++)
            PlW[(quad * 4 + r) * 72 + tt * 16 + l16] = f2bf(p[r][tt]);
    bf16x8 ap0 = *(const bf16x8*)&PlW[l16 * 72 + quad * 8];
    bf16x8 ap1 = *(const bf16x8*)&PlW[l16 * 72 + 32 + quad * 8];

    // ---- O += P V
#pragma unroll
    for (int cb = 0; cb < 4; cb++) {
        int rr = cb * 16 + l16;
        bf16x8 v0 = *(const bf16x8*)(Vs + (rr * 8 + (quad ^ r7)) * 8);
        bf16x8 v1 = *(const bf16x8*)(Vs + (rr * 8 + ((quad + 4) ^ r7)) * 8);
        o[cb] = __builtin_amdgcn_mfma_f32_16x16x32_bf16(ap0, v0, o[cb], 0, 0, 0);
        o[cb] = __builtin_amdgcn_mfma_f32_16x16x32_bf16(ap1, v1, o[cb], 0, 0, 0);
    }
}

__global__ __launch_bounds__(256) void attn_kernel(
    const unsigned short* __restrict__ Q,
    const unsigned short* __restrict__ K,
    const unsigned short* __restrict__ Vt,
    unsigned short* __restrict__ ctx)
{
    __shared__ unsigned short KV[2][8192];         // [buf][K:4096 | V:4096]
    __shared__ unsigned short Pl[2][4][16 * 72];   // [tile][wave]

    int t = threadIdx.x, w = t >> 6, lane = t & 63;
    int l16 = lane & 15, quad = lane >> 4;
    int r7 = l16 & 7;
    int bh = blockIdx.y;
    int b_ = bh >> 4, h = bh & 15;
    int pr = blockIdx.x;            // pair id 0..15
    int t1 = 31 - pr, t0 = pr;
    int nch = t1 + 1;               // 17..32 chunks; total work 33 units/block

    const unsigned short* Kg  = K  + (long)bh * NSEQ * HDIM;
    const unsigned short* Vtg = Vt + (long)bh * HDIM * NSEQ;

    const float log2e = 1.44269504f;
    float slope = exp2f(-0.5f * (float)(h + 1));
    float sc2 = 0.125f * log2e;     // scale * log2(e)
    float ss2 = slope * sc2;

    int qb1 = t1 * 64 + w * 16;
    int qb0 = t0 * 64 + w * 16;
    const unsigned short* qp1 = Q + ((long)bh * NSEQ + qb1 + l16) * HDIM + quad * 8;
    const unsigned short* qp0 = Q + ((long)bh * NSEQ + qb0 + l16) * HDIM + quad * 8;
    bf16x8 aq1_0 = *(const bf16x8*)qp1;
    bf16x8 aq1_1 = *(const bf16x8*)(qp1 + 32);
    bf16x8 aq0_0 = *(const bf16x8*)qp0;
    bf16x8 aq0_1 = *(const bf16x8*)(qp0 + 32);

    float m1[4], l1[4], m0[4], l0[4];
    f32x4 o1[4] = {}, o0[4] = {};
#pragma unroll
    for (int r = 0; r < 4; r++) {
        m1[r] = -1e30f; l1[r] = 0.0f;
        m0[r] = -1e30f; l0[r] = 0.0f;
    }

    stage_kv(Kg, Vtg, 0, KV[0], t);

    for (int c = 0; c < nch; c++) {
        __syncthreads();
        if (c + 1 < nch) stage_kv(Kg, Vtg, (c + 1) * 64, KV[(c + 1) & 1], t);

        const unsigned short* Ks = KV[c & 1];
        const unsigned short* Vs = KV[c & 1] + 4096;
        int kb = c * 64;

        attn_chunk(aq1_0, aq1_1, Ks, Vs, kb, qb1, c == nch - 1, sc2, ss2,
                   m1, l1, o1, &Pl[0][w][0], l16, quad, r7);
        if (c <= t0)
            attn_chunk(aq0_0, aq0_1, Ks, Vs, kb, qb0, c == t0, sc2, ss2,
                       m0, l0, o0, &Pl[1][w][0], l16, quad, r7);
    }

    // ---- normalize, store ctx [b, n, h, hd] for both tiles
#pragma unroll
    for (int r = 0; r < 4; r++) {
        float inv1 = 1.0f / l1[r];
        float inv0 = 1.0f / l0[r];
        int n1 = qb1 + quad * 4 + r;
        int n0_ = qb0 + quad * 4 + r;
        long base1 = (((long)b_ * NSEQ + n1) * NH + h) * HDIM;
        long base0 = (((long)b_ * NSEQ + n0_) * NH + h) * HDIM;
#pragma unroll
        for (int cb = 0; cb < 4; cb++) {
            ctx[base1 + cb * 16 + l16] = f2bf(o1[cb][r] * inv1);
            ctx[base0 + cb * 16 + l16] = f2bf(o0[cb][r] * inv0);
        }
    }
}

// ---------------------------------------------------------------------------
// Output projection (unchanged).
// ---------------------------------------------------------------------------
__global__ __launch_bounds__(256) void out_gemm_kernel(
    const unsigned short* __restrict__ A,
    const unsigned short* __restrict__ Bt,
    const float* __restrict__ bias,
    float* __restrict__ out)
{
    __shared__ unsigned short As[128 * 32];
    __shared__ unsigned short Bs[128 * 32];
    f32x4 acc[4][4] = {};
    int m0 = blockIdx.y * 128, n0 = blockIdx.x * 128;
    gemm_tile_128(A, Bt, m0, n0, As, Bs, acc);

    int t = threadIdx.x, wave = t >> 6, lane = t & 63;
    int l16 = lane & 15, quad = lane >> 4;
    int wm = wave >> 1, wn = wave & 1;
    int rg0 = m0 + wm * 64, cg0 = n0 + wn * 64;
#pragma unroll
    for (int c = 0; c < 4; c++) {
        float bc = bias[cg0 + c * 16 + l16];
#pragma unroll
        for (int r = 0; r < 4; r++)
#pragma unroll
            for (int reg = 0; reg < 4; reg++)
                out[(long)(rg0 + r * 16 + quad * 4 + reg) * DM + cg0 + c * 16 + l16] =
                    acc[r][c][reg] + bc;
    }
}

// ---------------------------------------------------------------------------
extern "C" void kernel_launch(void* const* d_in, const int* in_sizes, int n_in,
                              void* d_out, int out_size, void* d_ws, size_t ws_size,
                              hipStream_t stream)
{
    const float* x  = (const float*)d_in[0];
    const float* wq = (const float*)d_in[1];
    const float* wk = (const float*)d_in[2];
    const float* wv = (const float*)d_in[3];
    const float* wo = (const float*)d_in[4];
    const float* bo = (const float*)d_in[5];

    char* ws = (char*)d_ws;
    unsigned short* xb    = (unsigned short*)(ws);                 // 8 MiB
    unsigned short* wqkvt = (unsigned short*)(ws + (8L  << 20));   // 6 MiB [3072][1024]
    unsigned short* wot   = (unsigned short*)(ws + (14L << 20));   // 2 MiB
    unsigned short* Qb    = (unsigned short*)(ws + (16L << 20));   // 8 MiB
    unsigned short* Kb    = (unsigned short*)(ws + (24L << 20));   // 8 MiB
    unsigned short* Vt    = (unsigned short*)(ws + (32L << 20));   // 8 MiB
    unsigned short* ctx   = (unsigned short*)(ws + (40L << 20));   // 8 MiB
    float* out = (float*)d_out;

    convert_kernel<<<2048, 256, 0, stream>>>(x, wq, wk, wv, wo, xb, wqkvt, wot);

    qkv_gemm_kernel<<<dim3(3 * DM / 128, MROWS / 128), 256, 0, stream>>>(
        xb, wqkvt, Qb, Kb, Vt);

    attn_kernel<<<dim3(16, NB * NH), 256, 0, stream>>>(Qb, Kb, Vt, ctx);

    out_gemm_kernel<<<dim3(DM / 128, MROWS / 128), 256, 0, stream>>>(
        ctx, wot, bo, out);
}

// Round 6
// 209.744 us; speedup vs baseline: 2.9389x; 1.0810x over previous
//
#include <hip/hip_runtime.h>
#include <hip/hip_bf16.h>
#include <stdint.h>

#define NH 16
#define HDIM 64
#define NB 2
#define NSEQ 2048
#define DM 1024
#define MROWS (NB * NSEQ)   // 4096

typedef __attribute__((ext_vector_type(8))) short bf16x8;
typedef __attribute__((ext_vector_type(4))) float f32x4;

#define MFMA32(a, b, c) __builtin_amdgcn_mfma_f32_16x16x32_bf16(a, b, c, 0, 0, 0)

static __device__ __forceinline__ unsigned short f2bf(float f) {
    union { float f; unsigned u; } v;
    v.f = f;
    unsigned r = v.u + 0x7fffu + ((v.u >> 16) & 1u);   // RNE
    return (unsigned short)(r >> 16);
}

static __device__ __forceinline__ unsigned pack2bf(float a, float b) {
#if __has_builtin(__builtin_amdgcn_cvt_pk_bf16_f32)
    typedef __attribute__((ext_vector_type(2))) __bf16 bf2_t;
    union { bf2_t v; unsigned u; } c;
    c.v = __builtin_amdgcn_cvt_pk_bf16_f32(a, b);
    return c.u;
#else
    return (unsigned)f2bf(a) | ((unsigned)f2bf(b) << 16);
#endif
}

static __device__ __forceinline__ float fexp2(float x) {
#if __has_builtin(__builtin_amdgcn_exp2f)
    return __builtin_amdgcn_exp2f(x);
#else
    return exp2f(x);
#endif
}

typedef __attribute__((address_space(1))) void* gas_ptr;
typedef __attribute__((address_space(3))) void* las_ptr;

// async global->LDS, 16B per lane. LDS dest must be wave-uniform base + lane*16.
static __device__ __forceinline__ void load16_lds(const void* g, void* l) {
    __builtin_amdgcn_global_load_lds((gas_ptr)(uintptr_t)g, (las_ptr)(uintptr_t)l,
                                     16, 0, 0);
}

// ---------------------------------------------------------------------------
// Convert: x -> bf16 (blocks 0..1023), weights -> bf16 transposed via LDS
// tile transpose (blocks 1024..2047).
// ---------------------------------------------------------------------------
__global__ __launch_bounds__(256) void convert_kernel(
    const float* __restrict__ x,
    const float* __restrict__ wq, const float* __restrict__ wk,
    const float* __restrict__ wv, const float* __restrict__ wo,
    unsigned short* __restrict__ xb,
    unsigned short* __restrict__ wqkvt,
    unsigned short* __restrict__ wot)
{
    __shared__ unsigned short Ts[64][66];
    int t = threadIdx.x;
    int bx = blockIdx.x;
    if (bx < 1024) {
        const float4* xs = (const float4*)x + (long)bx * 1024;
        unsigned short* xd = xb + (long)bx * 4096;
#pragma unroll
        for (int i = 0; i < 4; i++) {
            float4 v = xs[i * 256 + t];
            ushort4 o;
            o.x = f2bf(v.x); o.y = f2bf(v.y); o.z = f2bf(v.z); o.w = f2bf(v.w);
            *(ushort4*)(xd + (i * 256 + t) * 4) = o;
        }
        return;
    }
    int wi = bx - 1024;
    int wsel = wi >> 8;                 // 0..3 = q,k,v,o
    int tile = wi & 255;
    int k0 = (tile >> 4) * 64, c0 = (tile & 15) * 64;
    const float* w = (wsel == 0) ? wq : (wsel == 1) ? wk : (wsel == 2) ? wv : wo;
    int lr = t >> 6, lc = t & 63;
#pragma unroll
    for (int rr = 0; rr < 16; rr++) {
        int row = rr * 4 + lr;
        Ts[row][lc] = f2bf(w[(long)(k0 + row) * DM + c0 + lc]);
    }
    __syncthreads();
    unsigned short* dst = (wsel == 3) ? wot : (wqkvt + (long)wsel * DM * DM);
#pragma unroll
    for (int rr = 0; rr < 16; rr++) {
        int crow = rr * 4 + lr;
        dst[(long)(c0 + crow) * DM + k0 + lc] = Ts[lc][crow];
    }
}

// ---------------------------------------------------------------------------
// m97-style 128x128 GEMM core (unchanged).
// ---------------------------------------------------------------------------
static __device__ __forceinline__ void gemm_tile_128(
    const unsigned short* __restrict__ A, const unsigned short* __restrict__ Bt,
    int m0, int n0, unsigned short* As, unsigned short* Bs, f32x4 (&acc)[4][4])
{
    int t = threadIdx.x;
    int lane = t & 63;
    int wave = t >> 6;
    int l16 = lane & 15, quad = lane >> 4;
    int wm = wave >> 1, wn = wave & 1;

    int off0 = t * 16;
    int off1 = off0 + 4096;
    const char* ga0 = (const char*)(A + (long)(m0 + (off0 >> 6)) * DM) + (off0 & 63);
    const char* ga1 = (const char*)(A + (long)(m0 + (off1 >> 6)) * DM) + (off1 & 63);
    const char* gb0 = (const char*)(Bt + (long)(n0 + (off0 >> 6)) * DM) + (off0 & 63);
    const char* gb1 = (const char*)(Bt + (long)(n0 + (off1 >> 6)) * DM) + (off1 & 63);
    char* sa0 = (char*)As + off0;
    char* sa1 = (char*)As + off1;
    char* sb0 = (char*)Bs + off0;
    char* sb1 = (char*)Bs + off1;

    const unsigned short* fa = As + (wm * 64 + l16) * 32 + quad * 8;
    const unsigned short* fb = Bs + (wn * 64 + l16) * 32 + quad * 8;

    for (int kk = 0; kk < DM; kk += 32) {
        load16_lds(ga0 + kk * 2, sa0);
        load16_lds(ga1 + kk * 2, sa1);
        load16_lds(gb0 + kk * 2, sb0);
        load16_lds(gb1 + kk * 2, sb1);
        __syncthreads();
        bf16x8 af[4], bf[4];
#pragma unroll
        for (int r = 0; r < 4; r++) af[r] = *(const bf16x8*)(fa + r * 16 * 32);
#pragma unroll
        for (int c = 0; c < 4; c++) bf[c] = *(const bf16x8*)(fb + c * 16 * 32);
#pragma unroll
        for (int r = 0; r < 4; r++)
#pragma unroll
            for (int c = 0; c < 4; c++)
                acc[r][c] = MFMA32(af[r], bf[c], acc[r][c]);
        __syncthreads();
    }
}

// ---------------------------------------------------------------------------
// Fused QKV GEMM (unchanged).
// ---------------------------------------------------------------------------
__global__ __launch_bounds__(256) void qkv_gemm_kernel(
    const unsigned short* __restrict__ A,
    const unsigned short* __restrict__ Bt,
    unsigned short* __restrict__ Qo, unsigned short* __restrict__ Ko,
    unsigned short* __restrict__ Vt)
{
    __shared__ unsigned short As[128 * 32];
    __shared__ unsigned short Bs[128 * 32];
    __shared__ unsigned short Tw[4][16][72];

    f32x4 acc[4][4] = {};
    int m0 = blockIdx.y * 128, n0 = blockIdx.x * 128;
    gemm_tile_128(A, Bt, m0, n0, As, Bs, acc);

    int t = threadIdx.x, wave = t >> 6, lane = t & 63;
    int l16 = lane & 15, quad = lane >> 4;
    int wm = wave >> 1, wn = wave & 1;
    int rg0 = m0 + wm * 64;
    int cg0 = n0 + wn * 64;
    int z = cg0 >> 10;
    int b_ = rg0 >> 11;
    int nb0 = rg0 & (NSEQ - 1);
    int h = (cg0 & 1023) >> 6;
    long bh = (long)(b_ * NH + h);

    if (z < 2) {
        unsigned short* dst = (z == 0 ? Qo : Ko) + bh * NSEQ * HDIM;
#pragma unroll
        for (int r = 0; r < 4; r++)
#pragma unroll
            for (int reg = 0; reg < 4; reg++) {
                long rowb = (long)(nb0 + r * 16 + quad * 4 + reg) * HDIM;
#pragma unroll
                for (int c = 0; c < 4; c++)
                    dst[rowb + c * 16 + l16] = f2bf(acc[r][c][reg]);
            }
    } else {
        unsigned short* dst = Vt + bh * HDIM * NSEQ;
#pragma unroll
        for (int c = 0; c < 4; c++) {
#pragma unroll
            for (int r = 0; r < 4; r++) {
                ushort4 u;
                u.x = f2bf(acc[r][c][0]); u.y = f2bf(acc[r][c][1]);
                u.z = f2bf(acc[r][c][2]); u.w = f2bf(acc[r][c][3]);
                *(ushort4*)&Tw[wave][l16][r * 16 + quad * 4] = u;   // [hd][n]
            }
#pragma unroll
            for (int j = 0; j < 4; j++) {
                int lrow = j * 4 + quad;
                ushort4 u = *(const ushort4*)&Tw[wave][lrow][l16 * 4];
                *(ushort4*)(dst + (long)(c * 16 + lrow) * NSEQ + nb0 + l16 * 4) = u;
            }
        }
    }
}

// ---------------------------------------------------------------------------
// Flash attention v4 (transposed): S^T = K·Q^T, O^T = V^T·P^T.
//  - P^T B-fragment is in-lane (cvt_pk packs), NO LDS round-trip for P.
//  - ALiBi folded into the QK mfma C-initializer (softmax row-shift
//    invariance lets us drop the per-row -slope*q term).
//  - m/l reductions are 2 shuffles (across quads) instead of 4.
//  - Pair fusion + double-buffered swizzled KV staging kept from round 5.
// ---------------------------------------------------------------------------
static __device__ __forceinline__ void stage_kv(
    const unsigned short* __restrict__ Kg,
    const unsigned short* __restrict__ Vtg,
    int kb, unsigned short* buf, int t)
{
#pragma unroll
    for (int r = 0; r < 2; r++) {
        int b = r * 256 + t;
        int row = b >> 3, sp = b & 7;
        int s = sp ^ (row & 7);
        load16_lds(Kg + (long)(kb + row) * HDIM + s * 8, buf + b * 8);
    }
#pragma unroll
    for (int r = 0; r < 2; r++) {
        int b = r * 256 + t;
        int row = b >> 3, sp = b & 7;
        int s = sp ^ (row & 7);
        load16_lds(Vtg + (long)row * NSEQ + kb + s * 8, buf + 4096 + b * 8);
    }
}

static __device__ __forceinline__ void attn_chunk2(
    const bf16x8& aq0, const bf16x8& aq1,
    const unsigned short* __restrict__ Ks,
    const unsigned short* __restrict__ Vs,
    const f32x4* __restrict__ cinit,
    int qb, int kb, bool last, float sc2,
    float& m_s, float& l_s, f32x4* o,
    int l16, int quad, int r7)
{
    // ---- S^T = K·Q^T + alibi-init : s[tt] holds key = kb+tt*16+quad*4+reg, q = l16
    f32x4 s[4];
#pragma unroll
    for (int tt = 0; tt < 4; tt++) {
        int rr = tt * 16 + l16;
        bf16x8 k0 = *(const bf16x8*)(Ks + (rr * 8 + (quad ^ r7)) * 8);
        bf16x8 k1 = *(const bf16x8*)(Ks + (rr * 8 + ((quad + 4) ^ r7)) * 8);
        f32x4 z = MFMA32(k0, aq0, cinit[tt]);
        s[tt] = MFMA32(k1, aq1, z);
    }

    // ---- causal mask, diagonal chunk only (wave-uniform branch)
    if (last) {
        int fdm = qb + l16 - kb - quad * 4;   // key offset tt*16+reg must be <= fdm
#pragma unroll
        for (int tt = 0; tt < 4; tt++)
#pragma unroll
            for (int r = 0; r < 4; r++)
                if (tt * 16 + r > fdm) s[tt][r] = -3e38f;
    }

    // ---- q-row max: in-lane 16 + 2 cross-quad shuffles
    f32x4 ma, mb;
#pragma unroll
    for (int r = 0; r < 4; r++) {
        ma[r] = fmaxf(s[0][r], s[1][r]);
        mb[r] = fmaxf(s[2][r], s[3][r]);
        ma[r] = fmaxf(ma[r], mb[r]);
    }
    float mv = fmaxf(fmaxf(ma[0], ma[1]), fmaxf(ma[2], ma[3]));
    mv = fmaxf(mv, __shfl_xor(mv, 16));
    mv = fmaxf(mv, __shfl_xor(mv, 32));
    float mnew = fmaxf(m_s, mv);
    float alpha = fexp2(sc2 * (m_s - mnew));
    m_s = mnew;
    float mm = -sc2 * mnew;

    // ---- exp (scale folded into the fma), sum
    f32x4 e[4];
#pragma unroll
    for (int tt = 0; tt < 4; tt++)
#pragma unroll
        for (int r = 0; r < 4; r++)
            e[tt][r] = fexp2(s[tt][r] * sc2 + mm);
    f32x4 s4;
#pragma unroll
    for (int r = 0; r < 4; r++)
        s4[r] = (e[0][r] + e[1][r]) + (e[2][r] + e[3][r]);
    float sum = (s4[0] + s4[1]) + (s4[2] + s4[3]);
    sum += __shfl_xor(sum, 16);
    sum += __shfl_xor(sum, 32);
    l_s = l_s * alpha + sum;

#pragma unroll
    for (int cb = 0; cb < 4; cb++)
#pragma unroll
        for (int r = 0; r < 4; r++)
            o[cb][r] *= alpha;

    // ---- P^T B-fragments: fully in-lane packs
    union { bf16x8 v; unsigned u[4]; } pb[2];
#pragma unroll
    for (int p = 0; p < 2; p++) {
        pb[p].u[0] = pack2bf(e[2 * p][0],     e[2 * p][1]);
        pb[p].u[1] = pack2bf(e[2 * p][2],     e[2 * p][3]);
        pb[p].u[2] = pack2bf(e[2 * p + 1][0], e[2 * p + 1][1]);
        pb[p].u[3] = pack2bf(e[2 * p + 1][2], e[2 * p + 1][3]);
    }

    // ---- O^T += V^T·P^T : A from two 8B swizzled LDS reads per mfma
    int q2 = quad >> 1, q1b = (quad & 1) << 3;
#pragma unroll
    for (int cb = 0; cb < 4; cb++) {
        int rd = cb * 16 + l16;
        const char* vrow = (const char*)(Vs + rd * 64);
        int x7 = rd & 7;
#pragma unroll
        for (int p = 0; p < 2; p++) {
            union { bf16x8 v; uint2 u2[2]; } a;
            int sb0 = 4 * p + q2;
            int sb1 = 4 * p + 2 + q2;
            a.u2[0] = *(const uint2*)(vrow + ((sb0 ^ x7) << 4) + q1b);
            a.u2[1] = *(const uint2*)(vrow + ((sb1 ^ x7) << 4) + q1b);
            o[cb] = MFMA32(a.v, pb[p].v, o[cb]);
        }
    }
}

__global__ __launch_bounds__(256) void attn_kernel(
    const unsigned short* __restrict__ Q,
    const unsigned short* __restrict__ K,
    const unsigned short* __restrict__ Vt,
    unsigned short* __restrict__ ctx)
{
    __shared__ unsigned short KV[2][8192];         // [buf][K:4096 | V:4096]

    int t = threadIdx.x, w = t >> 6, lane = t & 63;
    int l16 = lane & 15, quad = lane >> 4;
    int r7 = l16 & 7;
    int bh = blockIdx.y;
    int b_ = bh >> 4, h = bh & 15;
    int pr = blockIdx.x;            // pair id 0..15
    int t1 = 31 - pr, t0 = pr;
    int nch = t1 + 1;               // 17..32 chunks; total work 33 units/block

    const unsigned short* Kg  = K  + (long)bh * NSEQ * HDIM;
    const unsigned short* Vtg = Vt + (long)bh * HDIM * NSEQ;

    const float log2e = 1.44269504f;
    float slope = exp2f(-0.5f * (float)(h + 1));
    float sc2 = 0.125f * log2e;     // scale * log2(e)

    int qb1 = t1 * 64 + w * 16;
    int qb0 = t0 * 64 + w * 16;
    const unsigned short* qp1 = Q + ((long)bh * NSEQ + qb1 + l16) * HDIM + quad * 8;
    const unsigned short* qp0 = Q + ((long)bh * NSEQ + qb0 + l16) * HDIM + quad * 8;
    bf16x8 aq1_0 = *(const bf16x8*)qp1;
    bf16x8 aq1_1 = *(const bf16x8*)(qp1 + 32);
    bf16x8 aq0_0 = *(const bf16x8*)qp0;
    bf16x8 aq0_1 = *(const bf16x8*)(qp0 + 32);

    // alibi C-init: cinit[tt][reg] = slope * (kb + tt*16 + quad*4 + reg)
    f32x4 cinit[4];
#pragma unroll
    for (int tt = 0; tt < 4; tt++)
#pragma unroll
        for (int r = 0; r < 4; r++)
            cinit[tt][r] = slope * (float)(tt * 16 + quad * 4 + r);
    float sl64 = slope * 64.0f;

    float m1 = -1e30f, l1 = 0.0f, m0 = -1e30f, l0 = 0.0f;
    f32x4 o1[4] = {}, o0[4] = {};

    stage_kv(Kg, Vtg, 0, KV[0], t);

    for (int c = 0; c < nch; c++) {
        __syncthreads();
        if (c + 1 < nch) stage_kv(Kg, Vtg, (c + 1) * 64, KV[(c + 1) & 1], t);

        const unsigned short* Ks = KV[c & 1];
        const unsigned short* Vs = KV[c & 1] + 4096;
        int kb = c * 64;

        attn_chunk2(aq1_0, aq1_1, Ks, Vs, cinit, qb1, kb, c == nch - 1, sc2,
                    m1, l1, o1, l16, quad, r7);
        if (c <= t0)
            attn_chunk2(aq0_0, aq0_1, Ks, Vs, cinit, qb0, kb, c == t0, sc2,
                        m0, l0, o0, l16, quad, r7);

#pragma unroll
        for (int tt = 0; tt < 4; tt++)
#pragma unroll
            for (int r = 0; r < 4; r++)
                cinit[tt][r] += sl64;
    }

    // ---- normalize, store ctx [b, n=q, h, d]; lane holds q=l16, d=cb*16+quad*4+reg
    {
        float inv1 = 1.0f / l1;
        float inv0 = 1.0f / l0;
        long base1 = (((long)b_ * NSEQ + (qb1 + l16)) * NH + h) * HDIM + quad * 4;
        long base0 = (((long)b_ * NSEQ + (qb0 + l16)) * NH + h) * HDIM + quad * 4;
#pragma unroll
        for (int cb = 0; cb < 4; cb++) {
            uint2 u1, u0;
            u1.x = pack2bf(o1[cb][0] * inv1, o1[cb][1] * inv1);
            u1.y = pack2bf(o1[cb][2] * inv1, o1[cb][3] * inv1);
            u0.x = pack2bf(o0[cb][0] * inv0, o0[cb][1] * inv0);
            u0.y = pack2bf(o0[cb][2] * inv0, o0[cb][3] * inv0);
            *(uint2*)(ctx + base1 + cb * 16) = u1;
            *(uint2*)(ctx + base0 + cb * 16) = u0;
        }
    }
}

// ---------------------------------------------------------------------------
// Output projection (unchanged).
// ---------------------------------------------------------------------------
__global__ __launch_bounds__(256) void out_gemm_kernel(
    const unsigned short* __restrict__ A,
    const unsigned short* __restrict__ Bt,
    const float* __restrict__ bias,
    float* __restrict__ out)
{
    __shared__ unsigned short As[128 * 32];
    __shared__ unsigned short Bs[128 * 32];
    f32x4 acc[4][4] = {};
    int m0 = blockIdx.y * 128, n0 = blockIdx.x * 128;
    gemm_tile_128(A, Bt, m0, n0, As, Bs, acc);

    int t = threadIdx.x, wave = t >> 6, lane = t & 63;
    int l16 = lane & 15, quad = lane >> 4;
    int wm = wave >> 1, wn = wave & 1;
    int rg0 = m0 + wm * 64, cg0 = n0 + wn * 64;
#pragma unroll
    for (int c = 0; c < 4; c++) {
        float bc = bias[cg0 + c * 16 + l16];
#pragma unroll
        for (int r = 0; r < 4; r++)
#pragma unroll
            for (int reg = 0; reg < 4; reg++)
                out[(long)(rg0 + r * 16 + quad * 4 + reg) * DM + cg0 + c * 16 + l16] =
                    acc[r][c][reg] + bc;
    }
}

// ---------------------------------------------------------------------------
extern "C" void kernel_launch(void* const* d_in, const int* in_sizes, int n_in,
                              void* d_out, int out_size, void* d_ws, size_t ws_size,
                              hipStream_t stream)
{
    const float* x  = (const float*)d_in[0];
    const float* wq = (const float*)d_in[1];
    const float* wk = (const float*)d_in[2];
    const float* wv = (const float*)d_in[3];
    const float* wo = (const float*)d_in[4];
    const float* bo = (const float*)d_in[5];

    char* ws = (char*)d_ws;
    unsigned short* xb    = (unsigned short*)(ws);                 // 8 MiB
    unsigned short* wqkvt = (unsigned short*)(ws + (8L  << 20));   // 6 MiB [3072][1024]
    unsigned short* wot   = (unsigned short*)(ws + (14L << 20));   // 2 MiB
    unsigned short* Qb    = (unsigned short*)(ws + (16L << 20));   // 8 MiB
    unsigned short* Kb    = (unsigned short*)(ws + (24L << 20));   // 8 MiB
    unsigned short* Vt    = (unsigned short*)(ws + (32L << 20));   // 8 MiB
    unsigned short* ctx   = (unsigned short*)(ws + (40L << 20));   // 8 MiB
    float* out = (float*)d_out;

    convert_kernel<<<2048, 256, 0, stream>>>(x, wq, wk, wv, wo, xb, wqkvt, wot);

    qkv_gemm_kernel<<<dim3(3 * DM / 128, MROWS / 128), 256, 0, stream>>>(
        xb, wqkvt, Qb, Kb, Vt);

    attn_kernel<<<dim3(16, NB * NH), 256, 0, stream>>>(Qb, Kb, Vt, ctx);

    out_gemm_kernel<<<dim3(DM / 128, MROWS / 128), 256, 0, stream>>>(
        ctx, wot, bo, out);
}